// Round 4
// baseline (35.705 us; speedup 1.0000x reference)
//
#include <hip/hip_runtime.h>
#include <math.h>

// Problem constants (match reference)
#define B 8
#define N 500
#define K 16
#define D 32
#define C 16
#define T_IN 12
#define T_OUT 12
#define NNODE (B * N)

// Single fused kernel. Block = 256 threads = 4 waves; wave w owns node
// blockIdx.x*4 + w. Lane l: subgroup s = l&3, neighbor g = l>>2.
// One __syncthreads total (after weight staging); afterwards every wave is
// fully independent (k-compute, q-recompute, scores, mean, output are all
// wave-local; intra-wave LDS write->read ordered by the in-order DS pipe).
__global__ __launch_bounds__(256) void embed_gcn_one(
    const float* __restrict__ features,   // NNODE*D
    const float* __restrict__ input_seq,  // NNODE*T_IN
    const float* __restrict__ Wk,         // D*D
    const float* __restrict__ bk,         // D
    const float* __restrict__ Wq,         // D*D
    const float* __restrict__ bq,         // D
    const float* __restrict__ Wc,         // D*C
    const float* __restrict__ bc,         // C
    const float* __restrict__ Wcls,       // C*T_IN*T_OUT
    const int*   __restrict__ adj,        // NNODE*K
    float* __restrict__ out)              // NNODE*C*T_OUT
{
    const int tid  = threadIdx.x;
    const int w    = tid >> 6;            // wave / node slot
    const int l    = tid & 63;
    const int s    = l & 3;
    const int g    = l >> 2;              // neighbor slot 0..15
    const int node = blockIdx.x * 4 + w;
    const int b    = node / N;

    __shared__ __align__(16) float s_Wk[D * D];              // 4 KB
    __shared__ __align__(16) float s_Wq[D * D];              // 4 KB
    __shared__ __align__(16) float s_Wc[D * C];              // 2 KB
    __shared__ __align__(16) float s_Wcls[C * T_IN * T_OUT]; // 9 KB
    __shared__ float s_bk[D], s_bq[D], s_bc[C];
    __shared__ __align__(16) float s_fo[4][D];               // own features
    __shared__ __align__(16) float s_ft[4][K][36];           // fn, then tanh(k+q)
    __shared__ __align__(16) float s_x[4][K][T_IN];
    __shared__ __align__(16) float s_k[4][D];
    __shared__ float s_avg[4][C][T_IN];
    __shared__ int   s_id[4][K];
    __shared__ int   s_adj[4 * K];

    // ---- Phase 0: stage weights, adj, own features ----
    if (tid < 64) s_adj[tid] = adj[(size_t)blockIdx.x * 64 + tid];
    *(float4*)&s_Wk[tid * 4] = *(const float4*)&Wk[tid * 4];
    *(float4*)&s_Wq[tid * 4] = *(const float4*)&Wq[tid * 4];
    if (tid < 128) *(float4*)&s_Wc[tid * 4] = *(const float4*)&Wc[tid * 4];
    *(float4*)&s_Wcls[tid * 4]         = *(const float4*)&Wcls[tid * 4];
    *(float4*)&s_Wcls[1024 + tid * 4]  = *(const float4*)&Wcls[1024 + tid * 4];
    if (tid < 64) *(float4*)&s_Wcls[2048 + tid * 4] = *(const float4*)&Wcls[2048 + tid * 4];
    if (tid < D) { s_bk[tid] = bk[tid]; s_bq[tid] = bq[tid]; }
    if (tid < C) s_bc[tid] = bc[tid];
    if (tid < 32) *(float4*)&s_fo[0][tid * 4] =
        *(const float4*)&features[(size_t)blockIdx.x * 128 + tid * 4];
    __syncthreads();   // the only block-wide barrier

    // ---- Phase 1: gather neighbor features + input_seq; wave-local k ----
    const int j  = s_adj[w * 16 + g];
    const int jn = b * N + j;
    const float* __restrict__ fj = &features[(size_t)jn * D];
    const float4 f0 = *(const float4*)&fj[s * 8];
    const float4 f1 = *(const float4*)&fj[s * 8 + 4];
    float4 x4;
    if (s < 3) x4 = *(const float4*)&input_seq[(size_t)jn * T_IN + s * 4];

    // k for own node, computed by lanes 0..31 of the owning wave
    if (l < D) {
        float acc = s_bk[l];
        #pragma unroll
        for (int e = 0; e < D; ++e) acc += s_fo[w][e] * s_Wk[e * D + l];
        s_k[w][l] = acc;
    }

    *(float4*)&s_ft[w][g][s * 8]     = f0;
    *(float4*)&s_ft[w][g][s * 8 + 4] = f1;
    if (s < 3) *(float4*)&s_x[w][g][s * 4] = x4;

    // ---- Phase 2: q for neighbor (w,g), dims s*8..s*8+7; t = tanh(k+q) ----
    {
        float q[8];
        #pragma unroll
        for (int dd = 0; dd < 8; ++dd) q[dd] = s_bq[s * 8 + dd];
        #pragma unroll
        for (int e4 = 0; e4 < D; e4 += 4) {
            const float4 f = *(const float4*)&s_ft[w][g][e4];
            const float fv[4] = { f.x, f.y, f.z, f.w };
            #pragma unroll
            for (int ee = 0; ee < 4; ++ee) {
                const int e = e4 + ee;
                const float4 wa = *(const float4*)&s_Wq[e * D + s * 8];
                const float4 wb = *(const float4*)&s_Wq[e * D + s * 8 + 4];
                q[0] += fv[ee] * wa.x;  q[1] += fv[ee] * wa.y;
                q[2] += fv[ee] * wa.z;  q[3] += fv[ee] * wa.w;
                q[4] += fv[ee] * wb.x;  q[5] += fv[ee] * wb.y;
                q[6] += fv[ee] * wb.z;  q[7] += fv[ee] * wb.w;
            }
        }
        float t[8];
        #pragma unroll
        for (int dd = 0; dd < 8; ++dd)
            t[dd] = tanhf(s_k[w][s * 8 + dd] + q[dd]);
        float4 t0 = { t[0], t[1], t[2], t[3] };
        float4 t1 = { t[4], t[5], t[6], t[7] };
        *(float4*)&s_ft[w][g][s * 8]     = t0;   // overwrite fn in place
        *(float4*)&s_ft[w][g][s * 8 + 4] = t1;
    }

    // ---- Phase 3: class scores (lane s owns classes s*4..s*4+3) ----
    {
        float a0 = s_bc[s * 4 + 0];
        float a1 = s_bc[s * 4 + 1];
        float a2 = s_bc[s * 4 + 2];
        float a3 = s_bc[s * 4 + 3];
        #pragma unroll
        for (int ch = 0; ch < 8; ++ch) {
            const float4 t4 = *(const float4*)&s_ft[w][g][ch * 4];
            const float tv[4] = { t4.x, t4.y, t4.z, t4.w };
            #pragma unroll
            for (int dd = 0; dd < 4; ++dd) {
                const int d = ch * 4 + dd;
                const float4 w4 = *(const float4*)&s_Wc[d * C + s * 4];
                a0 += tv[dd] * w4.x;
                a1 += tv[dd] * w4.y;
                a2 += tv[dd] * w4.z;
                a3 += tv[dd] * w4.w;
            }
        }

        // softmax-replicated argmax over 16 classes (4 lanes x 4 local)
        float m = fmaxf(fmaxf(a0, a1), fmaxf(a2, a3));
        m = fmaxf(m, __shfl_xor(m, 1, 4));
        m = fmaxf(m, __shfl_xor(m, 2, 4));
        const float e0 = expf(a0 - m), e1 = expf(a1 - m);
        const float e2 = expf(a2 - m), e3 = expf(a3 - m);
        float sum = e0 + e1 + e2 + e3;
        sum += __shfl_xor(sum, 1, 4);
        sum += __shfl_xor(sum, 2, 4);
        const float p0 = e0 / sum, p1 = e1 / sum, p2 = e2 / sum, p3 = e3 / sum;

        float bp = p0; int bi = s * 4;
        if (p1 > bp) { bp = p1; bi = s * 4 + 1; }
        if (p2 > bp) { bp = p2; bi = s * 4 + 2; }
        if (p3 > bp) { bp = p3; bi = s * 4 + 3; }
        #pragma unroll
        for (int off = 1; off <= 2; off <<= 1) {
            const float op = __shfl_xor(bp, off, 4);
            const int   oi = __shfl_xor(bi, off, 4);
            if (op > bp || (op == bp && oi < bi)) { bp = op; bi = oi; }
        }
        if (s == 0) s_id[w][g] = bi;
    }

    // ---- Phase E: per-class masked mean (192 tasks, 3 per lane) ----
    {
        int ids[K];
        #pragma unroll
        for (int kk = 0; kk < K; ++kk) ids[kk] = s_id[w][kk];
        #pragma unroll
        for (int it = 0; it < 3; ++it) {
            const int id2 = l + it * 64;      // 0..191
            const int cc  = id2 / T_IN;
            const int t   = id2 - cc * T_IN;
            float sm = 0.f; int cnt = 0;
            #pragma unroll
            for (int kk = 0; kk < K; ++kk) {
                const bool hit = (ids[kk] == cc);
                const float xv = s_x[w][kk][t];
                if (hit) { sm += xv; ++cnt; }
            }
            s_avg[w][cc][t] = sm / (float)(cnt ? cnt : 1);
        }
    }

    // ---- Phase F: out = tanh(avg @ Wcls[cc]) (192 tasks, 3 per lane) ----
    #pragma unroll
    for (int it = 0; it < 3; ++it) {
        const int id2 = l + it * 64;          // 0..191 == cc*12 + o
        const int cc  = id2 / T_OUT;
        const int o   = id2 - cc * T_OUT;
        float acc = 0.f;
        #pragma unroll
        for (int t = 0; t < T_IN; ++t)
            acc += s_avg[w][cc][t] * s_Wcls[cc * (T_IN * T_OUT) + t * T_OUT + o];
        out[(size_t)node * (C * T_OUT) + id2] = tanhf(acc);
    }
}

extern "C" void kernel_launch(void* const* d_in, const int* in_sizes, int n_in,
                              void* d_out, int out_size, void* d_ws, size_t ws_size,
                              hipStream_t stream) {
    const float* features  = (const float*)d_in[0];
    const float* input_seq = (const float*)d_in[1];
    const float* Wk        = (const float*)d_in[2];
    const float* bk        = (const float*)d_in[3];
    const float* Wq        = (const float*)d_in[4];
    const float* bq        = (const float*)d_in[5];
    const float* Wc        = (const float*)d_in[6];
    const float* bc        = (const float*)d_in[7];
    const float* Wcls      = (const float*)d_in[8];
    const int*   adj       = (const int*)d_in[9];
    float*       out       = (float*)d_out;

    embed_gcn_one<<<NNODE / 4, 256, 0, stream>>>(
        features, input_seq, Wk, bk, Wq, bq, Wc, bc, Wcls, adj, out);
}

// Round 6
// 19.362 us; speedup vs baseline: 1.8441x; 1.8441x over previous
//
#include <hip/hip_runtime.h>
#include <math.h>

// Problem constants (match reference)
#define B 8
#define N 500
#define K 16
#define D 32
#define C 16
#define T_IN 12
#define T_OUT 12
#define NNODE (B * N)

// Quad-lane DPP permute (VALU pipe, no LDS). CTRL: quad_perm selector byte.
// Broadcast lane j of each aligned quad: CTRL = j * 0x55.
// XOR1 = 0xB1 ([1,0,3,2]), XOR2 = 0x4E ([2,3,0,1]).
template <int CTRL>
__device__ __forceinline__ float qperm(float v) {
    return __int_as_float(__builtin_amdgcn_update_dpp(
        0, __float_as_int(v), CTRL, 0xF, 0xF, true));
}

// ---------------- Kernel 1: k,q projections (16 nodes / block) -------------
// kq[node][0..31] = f @ Wk + bk ; kq[node][32..63] = f @ Wq + bq
// Thread: n = tid>>4 (node), m = (tid>>3)&1 (k/q), d4 = tid&7 (dim quad).
__global__ __launch_bounds__(256) void compute_kq(
    const float* __restrict__ features,   // NNODE*D
    const float* __restrict__ Wk,         // D*D
    const float* __restrict__ bk,         // D
    const float* __restrict__ Wq,         // D*D
    const float* __restrict__ bq,         // D
    float* __restrict__ kq)               // NNODE*64
{
    const int tid = threadIdx.x;
    __shared__ __align__(16) float s_W[2][D * D];  // row-major, as in global
    __shared__ __align__(16) float s_f[16][36];    // padded rows (144B, 16B-aligned)

    {
        const float4 wk4 = *(const float4*)&Wk[tid * 4];
        const float4 wq4 = *(const float4*)&Wq[tid * 4];
        *(float4*)&s_W[0][tid * 4] = wk4;
        *(float4*)&s_W[1][tid * 4] = wq4;
    }
    if (tid < 128) {
        const int n  = tid >> 3;
        const int e4 = tid & 7;
        *(float4*)&s_f[n][e4 * 4] =
            *(const float4*)&features[(size_t)blockIdx.x * 512 + tid * 4];
    }
    __syncthreads();

    const int n  = tid >> 4;          // 0..15
    const int m  = (tid >> 3) & 1;    // 0 = k, 1 = q
    const int d4 = tid & 7;           // dim quad
    const float* __restrict__ bias = m ? bq : bk;
    float4 acc = *(const float4*)&bias[d4 * 4];
    #pragma unroll
    for (int e4 = 0; e4 < 8; ++e4) {
        const float4 f = *(const float4*)&s_f[n][e4 * 4];
        const float fv[4] = { f.x, f.y, f.z, f.w };
        #pragma unroll
        for (int ee = 0; ee < 4; ++ee) {
            const float4 w4 = *(const float4*)&s_W[m][(e4 * 4 + ee) * D + d4 * 4];
            acc.x += fv[ee] * w4.x;  acc.y += fv[ee] * w4.y;
            acc.z += fv[ee] * w4.z;  acc.w += fv[ee] * w4.w;
        }
    }
    *(float4*)&kq[(size_t)(blockIdx.x * 16 + n) * 64 + m * 32 + d4 * 4] = acc;
}

// ---------------- Kernel 2: wave-per-node, near-zero LDS -------------------
// Block = 256 = 4 waves; wave w owns node blockIdx.x*4 + w.
// Lane l: s = l&3 (8 t-dims / 4 classes), g = l>>2 (neighbor). No barrier.
__global__ __launch_bounds__(256) void embed_gcn(
    const float* __restrict__ input_seq,  // NNODE*T_IN
    const float* __restrict__ Wc,         // D*C
    const float* __restrict__ bc,         // C
    const float* __restrict__ Wcls,       // C*T_IN*T_OUT
    const int*   __restrict__ adj,        // NNODE*K
    const float* __restrict__ kq,         // NNODE*64
    float* __restrict__ out)              // NNODE*C*T_OUT
{
    const int tid  = threadIdx.x;
    const int w    = tid >> 6;
    const int l    = tid & 63;
    const int s    = l & 3;
    const int g    = l >> 2;
    const int node = blockIdx.x * 4 + w;
    const int b    = node / N;

    __shared__ __align__(16) float s_xT[4][T_IN][16];  // [wave][t][neighbor]
    __shared__ __align__(16) int   s_id[4][16];

    // ---- Phase B: gathers + t = tanh(k+q) in registers ----
    const int j  = adj[(size_t)node * K + g];
    const int jn = b * N + j;
    const float4 q0 = *(const float4*)&kq[(size_t)jn * 64 + 32 + s * 8];
    const float4 q1 = *(const float4*)&kq[(size_t)jn * 64 + 36 + s * 8];
    const float4 k0 = *(const float4*)&kq[(size_t)node * 64 + s * 8];
    const float4 k1 = *(const float4*)&kq[(size_t)node * 64 + s * 8 + 4];
    if (s < 3) {
        const float4 x4 = *(const float4*)&input_seq[(size_t)jn * T_IN + s * 4];
        s_xT[w][s * 4 + 0][g] = x4.x;
        s_xT[w][s * 4 + 1][g] = x4.y;
        s_xT[w][s * 4 + 2][g] = x4.z;
        s_xT[w][s * 4 + 3][g] = x4.w;
    }
    const float t0 = tanhf(k0.x + q0.x), t1 = tanhf(k0.y + q0.y);
    const float t2 = tanhf(k0.z + q0.z), t3 = tanhf(k0.w + q0.w);
    const float t4 = tanhf(k1.x + q1.x), t5 = tanhf(k1.y + q1.y);
    const float t6 = tanhf(k1.z + q1.z), t7 = tanhf(k1.w + q1.w);

    // ---- Quad broadcast: tc<j>[i] = t[8j+i] in EVERY lane (absolute order) ----
    float tc0[8], tc1[8], tc2[8], tc3[8];
#define BC(dst, CTRL) \
    dst[0] = qperm<CTRL>(t0); dst[1] = qperm<CTRL>(t1); \
    dst[2] = qperm<CTRL>(t2); dst[3] = qperm<CTRL>(t3); \
    dst[4] = qperm<CTRL>(t4); dst[5] = qperm<CTRL>(t5); \
    dst[6] = qperm<CTRL>(t6); dst[7] = qperm<CTRL>(t7);
    BC(tc0, 0x00)  BC(tc1, 0x55)  BC(tc2, 0xAA)  BC(tc3, 0xFF)
#undef BC

    // ---- Phase C: scores for classes s*4..s*4+3, d ascending (bit-frozen) ----
    {
        const float4 bc4 = *(const float4*)&bc[s * 4];
        float a0 = bc4.x, a1 = bc4.y, a2 = bc4.z, a3 = bc4.w;
        const float* __restrict__ wcp = Wc + s * 4;
        #pragma unroll
        for (int i = 0; i < 8; ++i) {
            const float4 w4 = *(const float4*)&wcp[(i) * C];
            a0 += tc0[i] * w4.x; a1 += tc0[i] * w4.y; a2 += tc0[i] * w4.z; a3 += tc0[i] * w4.w;
        }
        #pragma unroll
        for (int i = 0; i < 8; ++i) {
            const float4 w4 = *(const float4*)&wcp[(8 + i) * C];
            a0 += tc1[i] * w4.x; a1 += tc1[i] * w4.y; a2 += tc1[i] * w4.z; a3 += tc1[i] * w4.w;
        }
        #pragma unroll
        for (int i = 0; i < 8; ++i) {
            const float4 w4 = *(const float4*)&wcp[(16 + i) * C];
            a0 += tc2[i] * w4.x; a1 += tc2[i] * w4.y; a2 += tc2[i] * w4.z; a3 += tc2[i] * w4.w;
        }
        #pragma unroll
        for (int i = 0; i < 8; ++i) {
            const float4 w4 = *(const float4*)&wcp[(24 + i) * C];
            a0 += tc3[i] * w4.x; a1 += tc3[i] * w4.y; a2 += tc3[i] * w4.z; a3 += tc3[i] * w4.w;
        }

        // softmax-replicated argmax (identical to passing rounds)
        float m = fmaxf(fmaxf(a0, a1), fmaxf(a2, a3));
        m = fmaxf(m, __shfl_xor(m, 1, 4));
        m = fmaxf(m, __shfl_xor(m, 2, 4));
        const float e0 = expf(a0 - m), e1 = expf(a1 - m);
        const float e2 = expf(a2 - m), e3 = expf(a3 - m);
        float sum = e0 + e1 + e2 + e3;
        sum += __shfl_xor(sum, 1, 4);
        sum += __shfl_xor(sum, 2, 4);
        const float p0 = e0 / sum, p1 = e1 / sum, p2 = e2 / sum, p3 = e3 / sum;

        float bp = p0; int bi = s * 4;
        if (p1 > bp) { bp = p1; bi = s * 4 + 1; }
        if (p2 > bp) { bp = p2; bi = s * 4 + 2; }
        if (p3 > bp) { bp = p3; bi = s * 4 + 3; }
        #pragma unroll
        for (int off = 1; off <= 2; off <<= 1) {
            const float op = __shfl_xor(bp, off, 4);
            const int   oi = __shfl_xor(bi, off, 4);
            if (op > bp || (op == bp && oi < bi)) { bp = op; bi = oi; }
        }
        if (s == 0) s_id[w][g] = bi;
    }

    // ---- Phase E: masked mean. Lane owns (cc = l>>2, t-triple tq = l&3) ----
    const int cc = l >> 2;
    const int tq = l & 3;
    const int tbase = tq * 3;

    const int4 i0 = *(const int4*)&s_id[w][0];
    const int4 i1 = *(const int4*)&s_id[w][4];
    const int4 i2 = *(const int4*)&s_id[w][8];
    const int4 i3 = *(const int4*)&s_id[w][12];
    float msk[16]; int cnt = 0;
    {
        const int idv[16] = { i0.x, i0.y, i0.z, i0.w,  i1.x, i1.y, i1.z, i1.w,
                              i2.x, i2.y, i2.z, i2.w,  i3.x, i3.y, i3.z, i3.w };
        #pragma unroll
        for (int kk = 0; kk < 16; ++kk) {
            const bool h = (idv[kk] == cc);
            msk[kk] = h ? 1.f : 0.f;
            cnt += h;
        }
    }
    const float fcnt = (cnt == 0) ? 1.f : (float)cnt;

    float av0, av1, av2;
#define CELL(avx, T) { \
    const float4 xa = *(const float4*)&s_xT[w][T][0]; \
    const float4 xb = *(const float4*)&s_xT[w][T][4]; \
    const float4 xc = *(const float4*)&s_xT[w][T][8]; \
    const float4 xd = *(const float4*)&s_xT[w][T][12]; \
    float sm = 0.f; \
    sm += msk[0]*xa.x;  sm += msk[1]*xa.y;  sm += msk[2]*xa.z;  sm += msk[3]*xa.w; \
    sm += msk[4]*xb.x;  sm += msk[5]*xb.y;  sm += msk[6]*xb.z;  sm += msk[7]*xb.w; \
    sm += msk[8]*xc.x;  sm += msk[9]*xc.y;  sm += msk[10]*xc.z; sm += msk[11]*xc.w; \
    sm += msk[12]*xd.x; sm += msk[13]*xd.y; sm += msk[14]*xd.z; sm += msk[15]*xd.w; \
    avx = sm / fcnt; }
    CELL(av0, tbase)  CELL(av1, tbase + 1)  CELL(av2, tbase + 2)
#undef CELL

    // ---- Phase F: out(cc,o) = tanh(sum_t avg_t * Wcls[cc][t][o]) ----
    // Lane holds t = tbase..tbase+2; partial over all 12 o; DPP butterfly over tq.
    const float* __restrict__ wcl = Wcls + ((size_t)cc * T_IN + tbase) * T_OUT;
    float p[12];
    {
        const float4 wA0 = *(const float4*)&wcl[0];
        const float4 wA1 = *(const float4*)&wcl[4];
        const float4 wA2 = *(const float4*)&wcl[8];
        p[0] = av0 * wA0.x;  p[1] = av0 * wA0.y;  p[2]  = av0 * wA0.z;  p[3]  = av0 * wA0.w;
        p[4] = av0 * wA1.x;  p[5] = av0 * wA1.y;  p[6]  = av0 * wA1.z;  p[7]  = av0 * wA1.w;
        p[8] = av0 * wA2.x;  p[9] = av0 * wA2.y;  p[10] = av0 * wA2.z;  p[11] = av0 * wA2.w;
        const float4 wB0 = *(const float4*)&wcl[12];
        const float4 wB1 = *(const float4*)&wcl[16];
        const float4 wB2 = *(const float4*)&wcl[20];
        p[0] += av1 * wB0.x;  p[1] += av1 * wB0.y;  p[2]  += av1 * wB0.z;  p[3]  += av1 * wB0.w;
        p[4] += av1 * wB1.x;  p[5] += av1 * wB1.y;  p[6]  += av1 * wB1.z;  p[7]  += av1 * wB1.w;
        p[8] += av1 * wB2.x;  p[9] += av1 * wB2.y;  p[10] += av1 * wB2.z;  p[11] += av1 * wB2.w;
        const float4 wC0 = *(const float4*)&wcl[24];
        const float4 wC1 = *(const float4*)&wcl[28];
        const float4 wC2 = *(const float4*)&wcl[32];
        p[0] += av2 * wC0.x;  p[1] += av2 * wC0.y;  p[2]  += av2 * wC0.z;  p[3]  += av2 * wC0.w;
        p[4] += av2 * wC1.x;  p[5] += av2 * wC1.y;  p[6]  += av2 * wC1.z;  p[7]  += av2 * wC1.w;
        p[8] += av2 * wC2.x;  p[9] += av2 * wC2.y;  p[10] += av2 * wC2.z;  p[11] += av2 * wC2.w;
    }
    #pragma unroll
    for (int o = 0; o < 12; ++o) {
        p[o] += qperm<0xB1>(p[o]);   // + partner tq^1
        p[o] += qperm<0x4E>(p[o]);   // + pair tq^2  -> full sum over t
    }
    #pragma unroll
    for (int i = 0; i < 3; ++i) {
        const float va = (tq & 1) ? p[3 + i] : p[i];
        const float vb = (tq & 1) ? p[9 + i] : p[6 + i];
        const float v  = (tq & 2) ? vb : va;
        out[(size_t)node * (C * T_OUT) + cc * T_OUT + tbase + i] = tanhf(v);
    }
}

extern "C" void kernel_launch(void* const* d_in, const int* in_sizes, int n_in,
                              void* d_out, int out_size, void* d_ws, size_t ws_size,
                              hipStream_t stream) {
    const float* features  = (const float*)d_in[0];
    const float* input_seq = (const float*)d_in[1];
    const float* Wk        = (const float*)d_in[2];
    const float* bk        = (const float*)d_in[3];
    const float* Wq        = (const float*)d_in[4];
    const float* bq        = (const float*)d_in[5];
    const float* Wc        = (const float*)d_in[6];
    const float* bc        = (const float*)d_in[7];
    const float* Wcls      = (const float*)d_in[8];
    const int*   adj       = (const int*)d_in[9];
    float*       out       = (float*)d_out;
    float*       kq        = (float*)d_ws;     // NNODE*64 floats = 1 MB

    compute_kq<<<NNODE / 16, 256, 0, stream>>>(features, Wk, bk, Wq, bq, kq);
    embed_gcn<<<NNODE / 4, 256, 0, stream>>>(input_seq, Wc, bc, Wcls, adj, kq, out);
}